// Round 1
// baseline (2016.251 us; speedup 1.0000x reference)
//
#include <hip/hip_runtime.h>
#include <hip/hip_bf16.h>
#include <cstdint>

#define B_   32
#define LQ_  2048
#define LK_  2048
#define D_   256
#define INV_T 0.0625f   // 1/16

typedef __attribute__((ext_vector_type(8))) short bf16x8;
typedef __attribute__((ext_vector_type(4))) float f32x4;

// fp32 -> bf16 round-to-nearest-even (bit trick)
__device__ __forceinline__ unsigned short f2bf(float f) {
    union { float f; unsigned u; } a; a.f = f;
    unsigned u = a.u;
    unsigned r = (u + 0x7FFFu + ((u >> 16) & 1u)) >> 16;
    return (unsigned short)r;
}

// pack 4 bf16 into one 8B word for a single ds_write_b64
__device__ __forceinline__ unsigned long long pack4bf(float a, float b, float c, float d) {
    return (unsigned long long)f2bf(a)
         | ((unsigned long long)f2bf(b) << 16)
         | ((unsigned long long)f2bf(c) << 32)
         | ((unsigned long long)f2bf(d) << 48);
}

// ---------------------------------------------------------------------------
// Kernel 1: P = mel ? 0 : exp((Q K^T)/16)  (unnormalized), rowsum += P
// (unchanged from previous round — byte-identical so pv delta is attributable)
// ---------------------------------------------------------------------------
__global__ __launch_bounds__(256) void qk_exp_kernel(
    const float* __restrict__ q, const float* __restrict__ kmat,
    const int* __restrict__ mel, float* __restrict__ attn,
    float* __restrict__ rowsum)
{
    const int b  = blockIdx.z;
    const int m0 = blockIdx.y * 128;
    const int n0 = blockIdx.x * 128;

    __shared__ unsigned short As[128][72];   // q tile, bf16, pad to 72
    __shared__ unsigned short Bs[128][72];   // k tile, bf16

    const int tid  = threadIdx.x;
    const int wave = tid >> 6, lane = tid & 63;
    const int wm   = wave >> 1, wn = wave & 1;
    const int quad = lane >> 4, l16 = lane & 15;

    f32x4 acc[4][4];
#pragma unroll
    for (int i = 0; i < 4; ++i)
#pragma unroll
        for (int j = 0; j < 4; ++j) acc[i][j] = (f32x4)(0.0f);

    const float* qb = q    + (size_t)b * LQ_ * D_;
    const float* kb = kmat + (size_t)b * LK_ * D_;

    const int sr = tid >> 4;         // 0..15
    const int sc = (tid & 15) * 4;   // 0..60

    for (int kt = 0; kt < 4; ++kt) {
        const int kbase = kt * 64;
#pragma unroll
        for (int p = 0; p < 8; ++p) {
            const int row = sr + p * 16;
            float4 va = *(const float4*)&qb[(size_t)(m0 + row) * D_ + kbase + sc];
            float4 vb = *(const float4*)&kb[(size_t)(n0 + row) * D_ + kbase + sc];
            As[row][sc+0] = f2bf(va.x); As[row][sc+1] = f2bf(va.y);
            As[row][sc+2] = f2bf(va.z); As[row][sc+3] = f2bf(va.w);
            Bs[row][sc+0] = f2bf(vb.x); Bs[row][sc+1] = f2bf(vb.y);
            Bs[row][sc+2] = f2bf(vb.z); Bs[row][sc+3] = f2bf(vb.w);
        }
        __syncthreads();
#pragma unroll
        for (int ks = 0; ks < 2; ++ks) {
            bf16x8 af[4], bfr[4];
#pragma unroll
            for (int i = 0; i < 4; ++i)
                af[i] = *(const bf16x8*)&As[wm*64 + i*16 + l16][ks*32 + quad*8];
#pragma unroll
            for (int j = 0; j < 4; ++j)
                bfr[j] = *(const bf16x8*)&Bs[wn*64 + j*16 + l16][ks*32 + quad*8];
#pragma unroll
            for (int i = 0; i < 4; ++i)
#pragma unroll
                for (int j = 0; j < 4; ++j)
                    acc[i][j] = __builtin_amdgcn_mfma_f32_16x16x32_bf16(
                        af[i], bfr[j], acc[i][j], 0, 0, 0);
        }
        __syncthreads();
    }

    // Epilogue: P = mel ? 0 : exp(s/16); write; accumulate row sums.
    float*      attnB = attn + (size_t)b * LQ_ * LK_;
    const int*  melB  = mel  + (size_t)b * LQ_ * LK_;

    float rs[4][4];
#pragma unroll
    for (int i = 0; i < 4; ++i)
#pragma unroll
        for (int r = 0; r < 4; ++r) rs[i][r] = 0.0f;

#pragma unroll
    for (int i = 0; i < 4; ++i) {
#pragma unroll
        for (int j = 0; j < 4; ++j) {
#pragma unroll
            for (int r = 0; r < 4; ++r) {
                const int row = wm*64 + i*16 + quad*4 + r;  // C/D: row = quad*4+reg
                const int col = wn*64 + j*16 + l16;         // C/D: col = lane&15
                const size_t gi = (size_t)(m0 + row) * LK_ + (n0 + col);
                float s = acc[i][j][r] * INV_T;
                float p = melB[gi] ? 0.0f : __expf(s);
                attnB[gi] = p;
                rs[i][r] += p;
            }
        }
    }

#pragma unroll
    for (int i = 0; i < 4; ++i) {
#pragma unroll
        for (int r = 0; r < 4; ++r) {
            float s = rs[i][r];
            s += __shfl_xor(s, 1);
            s += __shfl_xor(s, 2);
            s += __shfl_xor(s, 4);
            s += __shfl_xor(s, 8);
            if (l16 == 0) {
                const int row = wm*64 + i*16 + quad*4 + r;
                atomicAdd(&rowsum[(size_t)b * LQ_ + m0 + row], s);
            }
        }
    }
}

// ---------------------------------------------------------------------------
// Kernel 2 v2: a = src ? 0 : P/l; attn <- a (in place); O = a @ V
// Changes vs v1:
//   - unpadded XOR-chunk-swizzled LDS (key=(row^(row>>3))&7 on 16B chunks):
//     V^T staging writes drop from ~8-16-way bank conflict to 2-way,
//     frag reads stay conflict-free.
//   - invl[] LDS + its barrier removed (reciprocals held in 4 regs/thread)
//   - LDS = 40960 B exactly -> 4 blocks/CU (16 waves), enforced via
//     __launch_bounds__(256,4) (VGPR <= 128).
//   - explicit packed 8B ds_write_b64 stores for both LDS tiles.
// ---------------------------------------------------------------------------

// swizzled 16B-aligned frag pointer: row*128B + (chunk ^ key(row))*16B
__device__ __forceinline__ const bf16x8* lds_frag(
    const unsigned short (*arr)[64], int row, int chunk) {
    const int key = (row ^ (row >> 3)) & 7;
    return (const bf16x8*)&arr[row][(chunk ^ key) << 3];
}

// swizzled element offset for an 8B (4-elem) store at element index `e`
__device__ __forceinline__ int swz8(int row, int e) {
    return (e & 7) | ((((e >> 3) ^ row ^ (row >> 3)) & 7) << 3);
}

__global__ __launch_bounds__(256, 4) void pv_norm_kernel(
    const float* __restrict__ v, const int* __restrict__ src,
    const float* __restrict__ rowsum, float* __restrict__ attn,
    float* __restrict__ out)
{
    const int b  = blockIdx.y;
    const int m0 = blockIdx.x * 64;

    __shared__ unsigned short As[64][64];    // a tile, bf16 [m][k], swizzled
    __shared__ unsigned short Vt[256][64];   // V^T tile, bf16 [n][k], swizzled

    const int tid  = threadIdx.x;
    const int wave = tid >> 6, lane = tid & 63;
    const int wn   = wave;                  // 4 waves cover D in 64-col strips
    const int quad = lane >> 4, l16 = lane & 15;

    f32x4 acc[4][4];
#pragma unroll
    for (int i = 0; i < 4; ++i)
#pragma unroll
        for (int j = 0; j < 4; ++j) acc[i][j] = (f32x4)(0.0f);

    const float* vb    = v    + (size_t)b * LK_ * D_;
    float*       attnB = attn + (size_t)b * LQ_ * LK_;
    const int*   srcB  = src  + (size_t)b * LQ_ * LK_;

    const int sr = tid >> 4;         // 0..15
    const int sc = (tid & 15) * 4;   // 0..60

    // per-thread reciprocal row sums for the 4 rows this thread normalizes
    float il[4];
#pragma unroll
    for (int p = 0; p < 4; ++p)
        il[p] = 1.0f / rowsum[(size_t)b * LQ_ + m0 + sr + p * 16];

    for (int kt = 0; kt < 32; ++kt) {
        const int k0 = kt * 64;

        // Stage a-tile (64x64): read P, normalize, mask, write back, bf16->LDS.
        // (attn/src are HBM-latency loads: issued first so the V staging below
        //  overlaps their latency.)
#pragma unroll
        for (int p = 0; p < 4; ++p) {
            const int row = sr + p * 16;
            const size_t gi = (size_t)(m0 + row) * LK_ + k0 + sc;
            float4 pv = *(const float4*)&attnB[gi];
            int4   sv = *(const int4*)&srcB[gi];
            const float ilp = il[p];
            float a0 = sv.x ? 0.0f : pv.x * ilp;
            float a1 = sv.y ? 0.0f : pv.y * ilp;
            float a2 = sv.z ? 0.0f : pv.z * ilp;
            float a3 = sv.w ? 0.0f : pv.w * ilp;
            float4 st; st.x = a0; st.y = a1; st.z = a2; st.w = a3;
            *(float4*)&attnB[gi] = st;
            // 16 lanes cover one full row -> swizzle is a row permutation,
            // conflict-free ds_write_b64
            *(unsigned long long*)&As[row][swz8(row, sc)] = pack4bf(a0, a1, a2, a3);
        }

        // Stage V^T tile (64 k-rows x 256 d-cols) via 4x4 register transpose.
        // Global reads keep the coalesced mapping (16 lanes span a 256B row
        // segment); LDS writes land 2-way via the chunk swizzle.
#pragma unroll
        for (int p = 0; p < 4; ++p) {
            const int bi  = tid + p * 256;
            const int bkv = (bi >> 6) * 4;   // 0..60 (wave-uniform)
            const int bn  = (bi & 63) * 4;   // 0..252
            const float* s0 = &vb[(size_t)(k0 + bkv) * D_ + bn];
            float4 r0 = *(const float4*)(s0);
            float4 r1 = *(const float4*)(s0 + D_);
            float4 r2 = *(const float4*)(s0 + 2 * D_);
            float4 r3 = *(const float4*)(s0 + 3 * D_);
            *(unsigned long long*)&Vt[bn+0][swz8(bn+0, bkv)] = pack4bf(r0.x, r1.x, r2.x, r3.x);
            *(unsigned long long*)&Vt[bn+1][swz8(bn+1, bkv)] = pack4bf(r0.y, r1.y, r2.y, r3.y);
            *(unsigned long long*)&Vt[bn+2][swz8(bn+2, bkv)] = pack4bf(r0.z, r1.z, r2.z, r3.z);
            *(unsigned long long*)&Vt[bn+3][swz8(bn+3, bkv)] = pack4bf(r0.w, r1.w, r2.w, r3.w);
        }
        __syncthreads();

#pragma unroll
        for (int ks = 0; ks < 2; ++ks) {
            bf16x8 af[4], bfr[4];
            const int chunk = ks * 4 + quad;
#pragma unroll
            for (int i = 0; i < 4; ++i)
                af[i] = *lds_frag(As, i*16 + l16, chunk);
#pragma unroll
            for (int j = 0; j < 4; ++j)
                bfr[j] = *lds_frag(Vt, wn*64 + j*16 + l16, chunk);
#pragma unroll
            for (int i = 0; i < 4; ++i)
#pragma unroll
                for (int j = 0; j < 4; ++j)
                    acc[i][j] = __builtin_amdgcn_mfma_f32_16x16x32_bf16(
                        af[i], bfr[j], acc[i][j], 0, 0, 0);
        }
        __syncthreads();
    }

    // Epilogue: O tile 64 x 256
    float* outB = out + (size_t)b * LQ_ * D_;
#pragma unroll
    for (int i = 0; i < 4; ++i) {
#pragma unroll
        for (int j = 0; j < 4; ++j) {
#pragma unroll
            for (int r = 0; r < 4; ++r) {
                const int row = i*16 + quad*4 + r;
                const int col = wn*64 + j*16 + l16;
                outB[(size_t)(m0 + row) * D_ + col] = acc[i][j][r];
            }
        }
    }
}

extern "C" void kernel_launch(void* const* d_in, const int* in_sizes, int n_in,
                              void* d_out, int out_size, void* d_ws, size_t ws_size,
                              hipStream_t stream) {
    const float* q        = (const float*)d_in[0];
    const float* k        = (const float*)d_in[1];
    const float* v        = (const float*)d_in[2];
    const int*   src_mask = (const int*)d_in[3];
    const int*   mel_mask = (const int*)d_in[4];

    float* out  = (float*)d_out;                       // [B, LQ, D]
    float* attn = out + (size_t)B_ * LQ_ * D_;         // [B, LQ, LK]
    float* rowsum = (float*)d_ws;                      // [B, LQ]

    hipMemsetAsync(rowsum, 0, (size_t)B_ * LQ_ * sizeof(float), stream);

    qk_exp_kernel<<<dim3(LK_/128, LQ_/128, B_), 256, 0, stream>>>(
        q, k, mel_mask, attn, rowsum);

    pv_norm_kernel<<<dim3(LQ_/64, B_), 256, 0, stream>>>(
        v, src_mask, rowsum, attn, out);
}

// Round 2
// 1733.807 us; speedup vs baseline: 1.1629x; 1.1629x over previous
//
#include <hip/hip_runtime.h>
#include <hip/hip_bf16.h>
#include <cstdint>

#define B_   32
#define LQ_  2048
#define LK_  2048
#define D_   256
#define INV_T 0.0625f   // 1/16

typedef __attribute__((ext_vector_type(8))) short bf16x8;
typedef __attribute__((ext_vector_type(4))) float f32x4;

// fp32 -> bf16 round-to-nearest-even (bit trick)
__device__ __forceinline__ unsigned short f2bf(float f) {
    union { float f; unsigned u; } a; a.f = f;
    unsigned u = a.u;
    unsigned r = (u + 0x7FFFu + ((u >> 16) & 1u)) >> 16;
    return (unsigned short)r;
}

// pack 4 bf16 into one 8B word for a single ds_write_b64
__device__ __forceinline__ unsigned long long pack4bf(float a, float b, float c, float d) {
    return (unsigned long long)f2bf(a)
         | ((unsigned long long)f2bf(b) << 16)
         | ((unsigned long long)f2bf(c) << 32)
         | ((unsigned long long)f2bf(d) << 48);
}

// ---------------------------------------------------------------------------
// Kernel 1: P = mel ? 0 : exp((Q K^T)/16)  (unnormalized), rowsum += P
// v3: 1D grid + batch->XCD affinity decode (batch b pinned to XCD b%8 so the
// per-batch q+k panels (4 MB) stay L2-resident per XCD). Body unchanged.
// ---------------------------------------------------------------------------
__global__ __launch_bounds__(256) void qk_exp_kernel(
    const float* __restrict__ q, const float* __restrict__ kmat,
    const int* __restrict__ mel, float* __restrict__ attn,
    float* __restrict__ rowsum)
{
    // id = 0..8191; HW assigns XCD = id % 8 (round-robin dispatch).
    const int id  = blockIdx.x;
    const int xcd = id & 7;
    const int idx = id >> 3;                 // 0..1023
    const int b   = xcd + 8 * (idx >> 8);    // 4 batches per XCD, sequential
    const int t   = idx & 255;               // 16x16 tiles within batch
    const int m0  = (t >> 4) * 128;
    const int n0  = (t & 15) * 128;

    __shared__ unsigned short As[128][72];   // q tile, bf16, pad to 72
    __shared__ unsigned short Bs[128][72];   // k tile, bf16

    const int tid  = threadIdx.x;
    const int wave = tid >> 6, lane = tid & 63;
    const int wm   = wave >> 1, wn = wave & 1;
    const int quad = lane >> 4, l16 = lane & 15;

    f32x4 acc[4][4];
#pragma unroll
    for (int i = 0; i < 4; ++i)
#pragma unroll
        for (int j = 0; j < 4; ++j) acc[i][j] = (f32x4)(0.0f);

    const float* qb = q    + (size_t)b * LQ_ * D_;
    const float* kb = kmat + (size_t)b * LK_ * D_;

    const int sr = tid >> 4;         // 0..15
    const int sc = (tid & 15) * 4;   // 0..60

    for (int kt = 0; kt < 4; ++kt) {
        const int kbase = kt * 64;
#pragma unroll
        for (int p = 0; p < 8; ++p) {
            const int row = sr + p * 16;
            float4 va = *(const float4*)&qb[(size_t)(m0 + row) * D_ + kbase + sc];
            float4 vb = *(const float4*)&kb[(size_t)(n0 + row) * D_ + kbase + sc];
            As[row][sc+0] = f2bf(va.x); As[row][sc+1] = f2bf(va.y);
            As[row][sc+2] = f2bf(va.z); As[row][sc+3] = f2bf(va.w);
            Bs[row][sc+0] = f2bf(vb.x); Bs[row][sc+1] = f2bf(vb.y);
            Bs[row][sc+2] = f2bf(vb.z); Bs[row][sc+3] = f2bf(vb.w);
        }
        __syncthreads();
#pragma unroll
        for (int ks = 0; ks < 2; ++ks) {
            bf16x8 af[4], bfr[4];
#pragma unroll
            for (int i = 0; i < 4; ++i)
                af[i] = *(const bf16x8*)&As[wm*64 + i*16 + l16][ks*32 + quad*8];
#pragma unroll
            for (int j = 0; j < 4; ++j)
                bfr[j] = *(const bf16x8*)&Bs[wn*64 + j*16 + l16][ks*32 + quad*8];
#pragma unroll
            for (int i = 0; i < 4; ++i)
#pragma unroll
                for (int j = 0; j < 4; ++j)
                    acc[i][j] = __builtin_amdgcn_mfma_f32_16x16x32_bf16(
                        af[i], bfr[j], acc[i][j], 0, 0, 0);
        }
        __syncthreads();
    }

    // Epilogue: P = mel ? 0 : exp(s/16); write; accumulate row sums.
    float*      attnB = attn + (size_t)b * LQ_ * LK_;
    const int*  melB  = mel  + (size_t)b * LQ_ * LK_;

    float rs[4][4];
#pragma unroll
    for (int i = 0; i < 4; ++i)
#pragma unroll
        for (int r = 0; r < 4; ++r) rs[i][r] = 0.0f;

#pragma unroll
    for (int i = 0; i < 4; ++i) {
#pragma unroll
        for (int j = 0; j < 4; ++j) {
#pragma unroll
            for (int r = 0; r < 4; ++r) {
                const int row = wm*64 + i*16 + quad*4 + r;  // C/D: row = quad*4+reg
                const int col = wn*64 + j*16 + l16;         // C/D: col = lane&15
                const size_t gi = (size_t)(m0 + row) * LK_ + (n0 + col);
                float s = acc[i][j][r] * INV_T;
                float p = melB[gi] ? 0.0f : __expf(s);
                attnB[gi] = p;
                rs[i][r] += p;
            }
        }
    }

#pragma unroll
    for (int i = 0; i < 4; ++i) {
#pragma unroll
        for (int r = 0; r < 4; ++r) {
            float s = rs[i][r];
            s += __shfl_xor(s, 1);
            s += __shfl_xor(s, 2);
            s += __shfl_xor(s, 4);
            s += __shfl_xor(s, 8);
            if (l16 == 0) {
                const int row = wm*64 + i*16 + quad*4 + r;
                atomicAdd(&rowsum[(size_t)b * LQ_ + m0 + row], s);
            }
        }
    }
}

// ---------------------------------------------------------------------------
// Kernel 2 v3: a = src ? 0 : P/l; attn <- a (in place); O = a @ V
// Changes vs v2:
//   - batch->XCD affinity (1D grid decode): V working set per XCD becomes a
//     few 64KB tiles -> L2-resident -> kills the +340MB over-fetch.
//   - plain __launch_bounds__(256): VGPR back to ~130-160 (acc in VGPRs,
//     load ILP restored). 3 waves/SIMD expected — the faster r0 regime.
//   - T14-lite: next tile's attn/src prefetched into registers before the
//     barrier, hiding ~900cy HBM latency under V-stage + MFMA + barriers.
//   - keeps v2's XOR-chunk-swizzled LDS (conflict count already ~negligible)
//     and the register-held reciprocal rowsums.
// ---------------------------------------------------------------------------

// swizzled 16B-aligned frag pointer: row*128B + (chunk ^ key(row))*16B
__device__ __forceinline__ const bf16x8* lds_frag(
    const unsigned short (*arr)[64], int row, int chunk) {
    const int key = (row ^ (row >> 3)) & 7;
    return (const bf16x8*)&arr[row][(chunk ^ key) << 3];
}

// swizzled element offset for an 8B (4-elem) store at element index `e`
__device__ __forceinline__ int swz8(int row, int e) {
    return (e & 7) | ((((e >> 3) ^ row ^ (row >> 3)) & 7) << 3);
}

__global__ __launch_bounds__(256) void pv_norm_kernel(
    const float* __restrict__ v, const int* __restrict__ src,
    const float* __restrict__ rowsum, float* __restrict__ attn,
    float* __restrict__ out)
{
    // id = 0..1023; XCD = id % 8; batch pinned to XCD b%8.
    const int id  = blockIdx.x;
    const int xcd = id & 7;
    const int idx = id >> 3;                 // 0..127
    const int b   = xcd + 8 * (idx >> 5);    // 4 batches per XCD
    const int m0  = (idx & 31) * 64;         // 32 q-strips per batch

    __shared__ unsigned short As[64][64];    // a tile, bf16 [m][k], swizzled
    __shared__ unsigned short Vt[256][64];   // V^T tile, bf16 [n][k], swizzled

    const int tid  = threadIdx.x;
    const int wave = tid >> 6, lane = tid & 63;
    const int wn   = wave;                  // 4 waves cover D in 64-col strips
    const int quad = lane >> 4, l16 = lane & 15;

    f32x4 acc[4][4];
#pragma unroll
    for (int i = 0; i < 4; ++i)
#pragma unroll
        for (int j = 0; j < 4; ++j) acc[i][j] = (f32x4)(0.0f);

    const float* vb    = v    + (size_t)b * LK_ * D_;
    float*       attnB = attn + (size_t)b * LQ_ * LK_;
    const int*   srcB  = src  + (size_t)b * LQ_ * LK_;

    const int sr = tid >> 4;         // 0..15
    const int sc = (tid & 15) * 4;   // 0..60

    // per-thread reciprocal row sums for the 4 rows this thread normalizes
    float il[4];
#pragma unroll
    for (int p = 0; p < 4; ++p)
        il[p] = 1.0f / rowsum[(size_t)b * LQ_ + m0 + sr + p * 16];

    // --- prefetch tile kt=0 (attn + src) into registers ---
    float4 pv_r[4]; int4 sv_r[4];
#pragma unroll
    for (int p = 0; p < 4; ++p) {
        const int row = sr + p * 16;
        const size_t gi = (size_t)(m0 + row) * LK_ + sc;
        pv_r[p] = *(const float4*)&attnB[gi];
        sv_r[p] = *(const int4*)&srcB[gi];
    }

    for (int kt = 0; kt < 32; ++kt) {
        const int k0 = kt * 64;

        // Stage a-tile (64x64) from prefetched regs: normalize, mask,
        // write back fp32, packed bf16 ds_write_b64 (row-permuted swizzle,
        // conflict-free).
#pragma unroll
        for (int p = 0; p < 4; ++p) {
            const int row = sr + p * 16;
            const size_t gi = (size_t)(m0 + row) * LK_ + k0 + sc;
            const float ilp = il[p];
            float a0 = sv_r[p].x ? 0.0f : pv_r[p].x * ilp;
            float a1 = sv_r[p].y ? 0.0f : pv_r[p].y * ilp;
            float a2 = sv_r[p].z ? 0.0f : pv_r[p].z * ilp;
            float a3 = sv_r[p].w ? 0.0f : pv_r[p].w * ilp;
            float4 st; st.x = a0; st.y = a1; st.z = a2; st.w = a3;
            *(float4*)&attnB[gi] = st;
            *(unsigned long long*)&As[row][swz8(row, sc)] = pack4bf(a0, a1, a2, a3);
        }

        // Stage V^T tile (64 k-rows x 256 d-cols) via 4x4 register transpose.
        // With batch->XCD affinity these reads are L2-hot after first touch.
#pragma unroll
        for (int p = 0; p < 4; ++p) {
            const int bi  = tid + p * 256;
            const int bkv = (bi >> 6) * 4;   // 0..60 (wave-uniform)
            const int bn  = (bi & 63) * 4;   // 0..252
            const float* s0 = &vb[(size_t)(k0 + bkv) * D_ + bn];
            float4 r0 = *(const float4*)(s0);
            float4 r1 = *(const float4*)(s0 + D_);
            float4 r2 = *(const float4*)(s0 + 2 * D_);
            float4 r3 = *(const float4*)(s0 + 3 * D_);
            *(unsigned long long*)&Vt[bn+0][swz8(bn+0, bkv)] = pack4bf(r0.x, r1.x, r2.x, r3.x);
            *(unsigned long long*)&Vt[bn+1][swz8(bn+1, bkv)] = pack4bf(r0.y, r1.y, r2.y, r3.y);
            *(unsigned long long*)&Vt[bn+2][swz8(bn+2, bkv)] = pack4bf(r0.z, r1.z, r2.z, r3.z);
            *(unsigned long long*)&Vt[bn+3][swz8(bn+3, bkv)] = pack4bf(r0.w, r1.w, r2.w, r3.w);
        }

        // Prefetch next tile's attn/src (HBM-latency loads) BEFORE the
        // barrier so they overlap MFMA + both barriers + next a-stage.
        if (kt < 31) {
#pragma unroll
            for (int p = 0; p < 4; ++p) {
                const int row = sr + p * 16;
                const size_t gi = (size_t)(m0 + row) * LK_ + (k0 + 64) + sc;
                pv_r[p] = *(const float4*)&attnB[gi];
                sv_r[p] = *(const int4*)&srcB[gi];
            }
        }
        __syncthreads();

#pragma unroll
        for (int ks = 0; ks < 2; ++ks) {
            bf16x8 af[4], bfr[4];
            const int chunk = ks * 4 + quad;
#pragma unroll
            for (int i = 0; i < 4; ++i)
                af[i] = *lds_frag(As, i*16 + l16, chunk);
#pragma unroll
            for (int j = 0; j < 4; ++j)
                bfr[j] = *lds_frag(Vt, wn*64 + j*16 + l16, chunk);
#pragma unroll
            for (int i = 0; i < 4; ++i)
#pragma unroll
                for (int j = 0; j < 4; ++j)
                    acc[i][j] = __builtin_amdgcn_mfma_f32_16x16x32_bf16(
                        af[i], bfr[j], acc[i][j], 0, 0, 0);
        }
        __syncthreads();
    }

    // Epilogue: O tile 64 x 256
    float* outB = out + (size_t)b * LQ_ * D_;
#pragma unroll
    for (int i = 0; i < 4; ++i) {
#pragma unroll
        for (int j = 0; j < 4; ++j) {
#pragma unroll
            for (int r = 0; r < 4; ++r) {
                const int row = i*16 + quad*4 + r;
                const int col = wn*64 + j*16 + l16;
                outB[(size_t)(m0 + row) * D_ + col] = acc[i][j][r];
            }
        }
    }
}

extern "C" void kernel_launch(void* const* d_in, const int* in_sizes, int n_in,
                              void* d_out, int out_size, void* d_ws, size_t ws_size,
                              hipStream_t stream) {
    const float* q        = (const float*)d_in[0];
    const float* k        = (const float*)d_in[1];
    const float* v        = (const float*)d_in[2];
    const int*   src_mask = (const int*)d_in[3];
    const int*   mel_mask = (const int*)d_in[4];

    float* out  = (float*)d_out;                       // [B, LQ, D]
    float* attn = out + (size_t)B_ * LQ_ * D_;         // [B, LQ, LK]
    float* rowsum = (float*)d_ws;                      // [B, LQ]

    hipMemsetAsync(rowsum, 0, (size_t)B_ * LQ_ * sizeof(float), stream);

    qk_exp_kernel<<<dim3(16 * 16 * B_), 256, 0, stream>>>(
        q, k, mel_mask, attn, rowsum);

    pv_norm_kernel<<<dim3((LQ_ / 64) * B_), 256, 0, stream>>>(
        v, src_mask, rowsum, attn, out);
}